// Round 10
// baseline (209.662 us; speedup 1.0000x reference)
//
#include <hip/hip_runtime.h>
#include <hip/hip_bf16.h>
#include <math.h>

#define N_NODES 50000
#define N_EDGES 800000
#define F_DIM 128
#define H_DIM 64
#define IN_DIM 129   // F_DIM + 1 (binary feature)
#define NPAD 50176   // 196 * 256 (scan-padded node count)
#define ETOT (N_EDGES + N_NODES)          // 850000 CSR entries
#define PROJ_BLKS ((N_NODES + 63) / 64)   // 782
#define CNT_BLKS  391                     // 391*256*8 = 800768 >= E (8 edges/thread)
#define FILL_BLKS 831                     // 831*256*4 = 850944 >= ETOT (4/thread)

typedef __hip_bfloat16 bf16;
typedef unsigned short u16;
typedef __attribute__((ext_vector_type(8))) short bf16x8;   // MFMA A/B frag (4 VGPR)
typedef __attribute__((ext_vector_type(4))) float f32x4;    // MFMA C/D frag

static __device__ __forceinline__ float bs2f(short s) {
    union { float f; unsigned u; } c; c.u = ((unsigned)(unsigned short)s) << 16; return c.f;
}
static __device__ __forceinline__ short f2bs(float f) {
    union { bf16 b; short s; } u; u.b = __float2bfloat16(f); return u.s;
}

// ---------------------------------------------------------------------------
// Phase 1 (hybrid dispatch — overlap two independent jobs):
//  blocks [0, PROJ_BLKS):           [xl|xr] = x @ [Wl;Wr]^T + bias (MFMA)
//  blocks [PROJ_BLKS, +CNT_BLKS):   degree histogram + per-edge rank with
//                                   8-deep atomic ILP (8 edges/thread:
//                                   coalesced edst pre-load, then 8
//                                   independent returning atomics in flight)
// ---------------------------------------------------------------------------
__global__ __launch_bounds__(256) void phase1_kernel(
    const float* __restrict__ xf, const float* __restrict__ xb,
    const float* __restrict__ Wl, const float* __restrict__ bl,
    const float* __restrict__ Wr, const float* __restrict__ br,
    const int* __restrict__ edst,
    bf16* __restrict__ xl, bf16* __restrict__ xr,
    int* __restrict__ cnt, int* __restrict__ rank)
{
    if (blockIdx.x >= PROJ_BLKS) {
        const int t      = (blockIdx.x - PROJ_BLKS) * 256 + threadIdx.x;
        const int stride = CNT_BLKS * 256;
        int d[8];
        #pragma unroll
        for (int k = 0; k < 8; ++k) {
            int e = t + k * stride;
            d[k] = (e < N_EDGES) ? edst[e] : -1;
        }
        #pragma unroll
        for (int k = 0; k < 8; ++k) {
            int e = t + k * stride;
            if (d[k] >= 0) rank[e] = atomicAdd(&cnt[d[k]], 1);
        }
        return;
    }

    int wave = threadIdx.x >> 6;
    int lane = threadIdx.x & 63;
    int n = lane & 15, q = lane >> 4;
    int node0 = blockIdx.x * 64;

    // Build B-frags (hi/lo split of W rows) in registers from f32 W.
    bf16x8 bhi[2][4], blo[2][4];
    float biasv[2], w128[2];
    #pragma unroll
    for (int nt = 0; nt < 2; ++nt) {
        int ch = wave * 32 + nt * 16 + n;
        const float* wrow = (ch < 64) ? (Wl + (size_t)ch * IN_DIM)
                                      : (Wr + (size_t)(ch - 64) * IN_DIM);
        #pragma unroll
        for (int ks = 0; ks < 4; ++ks) {
            bf16x8 hi, lo;
            #pragma unroll
            for (int j = 0; j < 8; ++j) {
                float v = wrow[ks * 32 + q * 8 + j];
                short hs = f2bs(v);
                hi[j] = hs;
                lo[j] = f2bs(v - bs2f(hs));
            }
            bhi[nt][ks] = hi;
            blo[nt][ks] = lo;
        }
        biasv[nt] = (ch < 64) ? bl[ch] : br[ch - 64];
        w128[nt]  = wrow[128];
    }

    #pragma unroll
    for (int mt = 0; mt < 4; ++mt) {
        int nb = node0 + mt * 16;
        if (nb >= N_NODES) break;
        const float* xrow = xf + (size_t)(nb + n) * F_DIM;
        bf16x8 a[4];
        #pragma unroll
        for (int ks = 0; ks < 4; ++ks) {
            float4 u = *(const float4*)(xrow + ks * 32 + q * 8);
            float4 v = *(const float4*)(xrow + ks * 32 + q * 8 + 4);
            bf16x8 t;
            t[0] = f2bs(u.x); t[1] = f2bs(u.y); t[2] = f2bs(u.z); t[3] = f2bs(u.w);
            t[4] = f2bs(v.x); t[5] = f2bs(v.y); t[6] = f2bs(v.z); t[7] = f2bs(v.w);
            a[ks] = t;
        }
        f32x4 acc[2] = {{0.f,0.f,0.f,0.f},{0.f,0.f,0.f,0.f}};
        #pragma unroll
        for (int ks = 0; ks < 4; ++ks) {
            #pragma unroll
            for (int nt = 0; nt < 2; ++nt) {
                acc[nt] = __builtin_amdgcn_mfma_f32_16x16x32_bf16(a[ks], bhi[nt][ks], acc[nt], 0, 0, 0);
                acc[nt] = __builtin_amdgcn_mfma_f32_16x16x32_bf16(a[ks], blo[nt][ks], acc[nt], 0, 0, 0);
            }
        }
        float4 xbv = *(const float4*)(xb + nb + q * 4);
        float xbr[4] = {xbv.x, xbv.y, xbv.z, xbv.w};
        #pragma unroll
        for (int nt = 0; nt < 2; ++nt) {
            int ch = wave * 32 + nt * 16 + n;
            bf16* dstp = (ch < 64) ? xl : xr;
            int cc = ch & 63;
            #pragma unroll
            for (int r = 0; r < 4; ++r) {
                int node = nb + q * 4 + r;   // C/D: row = quad*4 + reg
                float val = acc[nt][r] + xbr[r] * w128[nt] + biasv[nt];
                dstp[(size_t)node * H_DIM + cc] = __float2bfloat16(val);
            }
        }
    }
}

// ---------------------------------------------------------------------------
// CSR scan (deg+1 per node: slot 0 of each segment = self-loop).
// offs is block-local exclusive; consumers add bsum[node>>8].
// ---------------------------------------------------------------------------
__global__ __launch_bounds__(256) void scan_a_kernel(
    const int* __restrict__ cnt, int* __restrict__ offs, int* __restrict__ bsum)
{
    __shared__ int s[256];
    int tid = threadIdx.x;
    int i = blockIdx.x * 256 + tid;
    int v = (i < N_NODES) ? cnt[i] + 1 : 0;    // +1 = self-loop slot
    s[tid] = v;
    __syncthreads();
    #pragma unroll
    for (int d = 1; d < 256; d <<= 1) {
        int t = (tid >= d) ? s[tid - d] : 0;
        __syncthreads();
        s[tid] += t;
        __syncthreads();
    }
    offs[i] = s[tid] - v;
    if (tid == 255) bsum[blockIdx.x] = s[255];
}

__global__ __launch_bounds__(256) void scan_b_kernel(int* __restrict__ bsum)
{
    __shared__ int s[256];
    int tid = threadIdx.x;
    int v = (tid < 196) ? bsum[tid] : 0;
    s[tid] = v;
    __syncthreads();
    #pragma unroll
    for (int d = 1; d < 256; d <<= 1) {
        int t = (tid >= d) ? s[tid - d] : 0;
        __syncthreads();
        s[tid] += t;
        __syncthreads();
    }
    if (tid < 196) bsum[tid] = s[tid] - v;
}

// ---------------------------------------------------------------------------
// K2a: CSR fill, atomic-free, uint16 entries (src < 65536), 4 edges/thread
// grid-stride -> 4 independent scattered stores in flight. 2 B scatter
// halves the per-segment line footprint vs int32.
// ---------------------------------------------------------------------------
__global__ __launch_bounds__(256) void fill_kernel(
    const int* __restrict__ esrc, const int* __restrict__ edst,
    const int* __restrict__ offs, const int* __restrict__ bsum,
    const int* __restrict__ rank, u16* __restrict__ csr_src)
{
    const int t      = blockIdx.x * 256 + threadIdx.x;
    const int stride = FILL_BLKS * 256;
    #pragma unroll
    for (int k = 0; k < 4; ++k) {
        int id = t + k * stride;
        if (id >= ETOT) continue;
        int src, pos;
        if (id < N_EDGES) {
            src = esrc[id];
            int dst = edst[id];
            pos = offs[dst] + bsum[dst >> 8] + 1 + rank[id];
        } else {
            src = id - N_EDGES;
            pos = offs[src] + bsum[src >> 8];
        }
        csr_src[pos] = (u16)src;
    }
}

// ---------------------------------------------------------------------------
// K2b (fused score + aggregate, wave-per-dst, depth-3 pipeline):
// 2-D lane layout: g = lane>>3 (edge slot, 8/batch), c8 = lane&7 (channel
// octet). Values for batches +1/+2 in flight; indices for +3.
// Dot reduce = 3 shfl_xor per batch; group-combine once per dst.
// ---------------------------------------------------------------------------
__global__ __launch_bounds__(256) void agg_fused(
    const u16* __restrict__ csr_src, const int* __restrict__ offs,
    const int* __restrict__ bsum,
    const bf16* __restrict__ xl, const bf16* __restrict__ xr,
    const float* __restrict__ att, const float* __restrict__ gb,
    bf16* __restrict__ h)
{
    int wid  = (blockIdx.x * 256 + threadIdx.x) >> 6;   // dst node
    int lane = threadIdx.x & 63;
    if (wid >= N_NODES) return;
    int g  = lane >> 3;   // edge slot within batch
    int c8 = lane & 7;    // channel octet

    float attv[8], xrv[8];
    {
        bf16x8 xrow = *(const bf16x8*)(xr + (size_t)wid * H_DIM + c8 * 8);
        float4 a0 = *(const float4*)(att + c8 * 8);
        float4 a1 = *(const float4*)(att + c8 * 8 + 4);
        attv[0] = a0.x; attv[1] = a0.y; attv[2] = a0.z; attv[3] = a0.w;
        attv[4] = a1.x; attv[5] = a1.y; attv[6] = a1.z; attv[7] = a1.w;
        #pragma unroll
        for (int j = 0; j < 8; ++j) xrv[j] = bs2f(xrow[j]);
    }

    int beg = offs[wid] + bsum[wid >> 8];
    int end = offs[wid + 1] + bsum[(wid + 1) >> 8];   // >= beg+1 (self-loop)
    int last = end - 1;
    float den = 0.f;
    float acc[8] = {0.f, 0.f, 0.f, 0.f, 0.f, 0.f, 0.f, 0.f};

    int i0 = beg + g;        i0 = (i0 < end) ? i0 : last;
    int i1 = beg + 8 + g;    i1 = (i1 < end) ? i1 : last;
    int i2 = beg + 16 + g;   i2 = (i2 < end) ? i2 : last;
    int srcC = csr_src[i2];                                    // idx batch+2
    bf16x8 xa = *(const bf16x8*)(xl + (size_t)(int)csr_src[i0] * H_DIM + c8 * 8);
    bf16x8 xb = *(const bf16x8*)(xl + (size_t)(int)csr_src[i1] * H_DIM + c8 * 8);

    for (int base = beg; base < end; base += 8) {
        int i3 = base + 24 + g;  i3 = (i3 < end) ? i3 : last;
        int srcD = csr_src[i3];                                // idx batch+3
        bf16x8 xc = *(const bf16x8*)(xl + (size_t)srcC * H_DIM + c8 * 8);

        bool valid = (base + g) < end;
        float xv[8], p = 0.f;
        #pragma unroll
        for (int j = 0; j < 8; ++j) {
            xv[j] = bs2f(xa[j]);
            float m = xv[j] + xrv[j];
            m = (m > 0.f) ? m : 0.2f * m;
            p += m * attv[j];
        }
        p += __shfl_xor(p, 1);
        p += __shfl_xor(p, 2);
        p += __shfl_xor(p, 4);      // all lanes of group g now hold p_g
        float ex = valid ? __expf(p) : 0.f;
        den += ex;
        #pragma unroll
        for (int j = 0; j < 8; ++j) acc[j] += ex * xv[j];

        xa = xb;
        xb = xc;
        srcC = srcD;
    }

    // combine the 8 edge-groups (once per dst)
    #pragma unroll
    for (int j = 0; j < 8; ++j) {
        acc[j] += __shfl_xor(acc[j], 8);
        acc[j] += __shfl_xor(acc[j], 16);
        acc[j] += __shfl_xor(acc[j], 32);
    }
    den += __shfl_xor(den, 8);
    den += __shfl_xor(den, 16);
    den += __shfl_xor(den, 32);

    if (g == 0) {
        float inv = 1.0f / den;
        float4 g0 = *(const float4*)(gb + c8 * 8);
        float4 g1 = *(const float4*)(gb + c8 * 8 + 4);
        float gbv[8] = {g0.x, g0.y, g0.z, g0.w, g1.x, g1.y, g1.z, g1.w};
        bf16x8 ov;
        #pragma unroll
        for (int j = 0; j < 8; ++j) {
            float v = acc[j] * inv + gbv[j];
            v = (v > 0.f) ? v : expm1f(v);
            ov[j] = f2bs(v);
        }
        *(bf16x8*)(h + (size_t)wid * H_DIM + c8 * 8) = ov;
    }
}

// ---------------------------------------------------------------------------
// K3 (MFMA): logits = h @ Wo^T + bo (+ softplus(dispersion) tail on block 0).
// B-frags (Wo hi/lo) built in registers from f32 Wo, once per block.
// ---------------------------------------------------------------------------
__global__ __launch_bounds__(256) void out_mfma(
    const bf16* __restrict__ h, const float* __restrict__ Wo,
    const float* __restrict__ bo, const float* __restrict__ disp,
    float* __restrict__ out)
{
    if (blockIdx.x == 0 && threadIdx.x < F_DIM) {
        float d = disp[threadIdx.x];
        out[(size_t)N_NODES * F_DIM + threadIdx.x] = (d > 20.f) ? d : log1pf(__expf(d));
    }

    int wave = threadIdx.x >> 6;
    int lane = threadIdx.x & 63;
    int n = lane & 15, q = lane >> 4;
    int node0 = blockIdx.x * 64;

    bf16x8 bhi[2][2], blo[2][2];
    float bov[2];
    #pragma unroll
    for (int nt = 0; nt < 2; ++nt) {
        int ch = wave * 32 + nt * 16 + n;
        const float* wrow = Wo + (size_t)ch * H_DIM;
        #pragma unroll
        for (int ks = 0; ks < 2; ++ks) {
            float4 u = *(const float4*)(wrow + ks * 32 + q * 8);
            float4 v = *(const float4*)(wrow + ks * 32 + q * 8 + 4);
            float w[8] = {u.x, u.y, u.z, u.w, v.x, v.y, v.z, v.w};
            bf16x8 hi, lo;
            #pragma unroll
            for (int j = 0; j < 8; ++j) {
                short hs = f2bs(w[j]);
                hi[j] = hs;
                lo[j] = f2bs(w[j] - bs2f(hs));
            }
            bhi[nt][ks] = hi;
            blo[nt][ks] = lo;
        }
        bov[nt] = bo[ch];
    }

    #pragma unroll
    for (int mt = 0; mt < 4; ++mt) {
        int nb = node0 + mt * 16;
        if (nb >= N_NODES) break;
        const bf16* hrow = h + (size_t)(nb + n) * H_DIM;
        bf16x8 a[2];
        #pragma unroll
        for (int ks = 0; ks < 2; ++ks)
            a[ks] = *(const bf16x8*)(hrow + ks * 32 + q * 8);
        f32x4 acc[2] = {{0.f,0.f,0.f,0.f},{0.f,0.f,0.f,0.f}};
        #pragma unroll
        for (int ks = 0; ks < 2; ++ks) {
            #pragma unroll
            for (int nt = 0; nt < 2; ++nt) {
                acc[nt] = __builtin_amdgcn_mfma_f32_16x16x32_bf16(a[ks], bhi[nt][ks], acc[nt], 0, 0, 0);
                acc[nt] = __builtin_amdgcn_mfma_f32_16x16x32_bf16(a[ks], blo[nt][ks], acc[nt], 0, 0, 0);
            }
        }
        #pragma unroll
        for (int nt = 0; nt < 2; ++nt) {
            int ch = wave * 32 + nt * 16 + n;
            #pragma unroll
            for (int r = 0; r < 4; ++r) {
                int node = nb + q * 4 + r;
                out[(size_t)node * F_DIM + ch] = acc[nt][r] + bov[nt];
            }
        }
    }
}

// ---------------------------------------------------------------------------
extern "C" void kernel_launch(void* const* d_in, const int* in_sizes, int n_in,
                              void* d_out, int out_size, void* d_ws, size_t ws_size,
                              hipStream_t stream)
{
    const float* xf  = (const float*)d_in[0];
    const float* xb  = (const float*)d_in[1];
    const int*   ei  = (const int*)d_in[2];    // [2, E] int32, row-major
    const float* Wl  = (const float*)d_in[3];
    const float* bl  = (const float*)d_in[4];
    const float* Wr  = (const float*)d_in[5];
    const float* br  = (const float*)d_in[6];
    const float* att = (const float*)d_in[7];
    const float* gb  = (const float*)d_in[8];
    const float* Wo  = (const float*)d_in[9];
    const float* bo  = (const float*)d_in[10];
    const float* dp  = (const float*)d_in[11];
    float* out = (float*)d_out;
    const int* esrc = ei;
    const int* edst = ei + N_EDGES;

    // ws layout (16B-aligned segments):
    //  xl bf16[N*64] | xr bf16[N*64] | h bf16[N*64] | csr_src u16[ETOT] |
    //  rank int[E] | cnt int[NPAD] | offs int[NPAD] | bsum int[256]
    char* ws = (char*)d_ws;
    const size_t SZB = (size_t)N_NODES * H_DIM * sizeof(bf16);   // 6.4 MB
    bf16*  xl      = (bf16*)(ws);
    bf16*  xr      = (bf16*)(ws + SZB);
    bf16*  h       = (bf16*)(ws + 2 * SZB);
    u16*   csr_src = (u16*)(ws + 3 * SZB);
    int*   rank    = (int*)(ws + 3 * SZB + (size_t)((ETOT + 1) & ~1) * 2);
    int*   cnt     = rank + N_EDGES;
    int*   offs    = cnt + NPAD;
    int*   bsum    = offs + NPAD;

    hipMemsetAsync(cnt, 0, NPAD * sizeof(int), stream);

    phase1_kernel<<<PROJ_BLKS + CNT_BLKS, 256, 0, stream>>>(
        xf, xb, Wl, bl, Wr, br, edst, xl, xr, cnt, rank);

    scan_a_kernel<<<NPAD / 256, 256, 0, stream>>>(cnt, offs, bsum);
    scan_b_kernel<<<1, 256, 0, stream>>>(bsum);

    fill_kernel<<<FILL_BLKS, 256, 0, stream>>>(esrc, edst, offs, bsum,
                                               rank, csr_src);

    agg_fused<<<(N_NODES * 64) / 256, 256, 0, stream>>>(csr_src, offs, bsum,
                                                        xl, xr, att, gb, h);

    out_mfma<<<(N_NODES + 63) / 64, 256, 0, stream>>>(h, Wo, bo, dp, out);
}

// Round 11
// 206.429 us; speedup vs baseline: 1.0157x; 1.0157x over previous
//
#include <hip/hip_runtime.h>
#include <hip/hip_bf16.h>
#include <math.h>

#define N_NODES 50000
#define N_EDGES 800000
#define F_DIM 128
#define H_DIM 64
#define IN_DIM 129   // F_DIM + 1 (binary feature)
#define NPAD 50176   // 196 * 256 (scan-padded node count)
#define ETOT (N_EDGES + N_NODES)          // 850000 CSR entries
#define PROJ_BLKS ((N_NODES + 63) / 64)   // 782
#define CNT_BLKS  ((N_EDGES + 255) / 256) // 3125 (1 edge/thread)
#define FILL_BLKS 831                     // 831*256*4 = 850944 >= ETOT (4/thread)

typedef __hip_bfloat16 bf16;
typedef unsigned short u16;
typedef __attribute__((ext_vector_type(8))) short bf16x8;   // MFMA A/B frag (4 VGPR)
typedef __attribute__((ext_vector_type(4))) float f32x4;    // MFMA C/D frag

static __device__ __forceinline__ float bs2f(short s) {
    union { float f; unsigned u; } c; c.u = ((unsigned)(unsigned short)s) << 16; return c.f;
}
static __device__ __forceinline__ short f2bs(float f) {
    union { bf16 b; short s; } u; u.b = __float2bfloat16(f); return u.s;
}

// ---------------------------------------------------------------------------
// Phase 1 (hybrid dispatch — overlap two independent jobs):
//  blocks [0, PROJ_BLKS):           [xl|xr] = x @ [Wl;Wr]^T + bias (MFMA)
//  blocks [PROJ_BLKS, +CNT_BLKS):   degree histogram + per-edge rank into
//    PER-XCD counter copies (copy = blockIdx & 7, the XCD round-robin
//    heuristic): each copy's lines stay owned by one XCD's L2, avoiding
//    cross-die atomic ping-pong. rank packs (copy<<16)|local_rank.
//    Correct for ANY block->XCD mapping (disjoint copies, merged in scan).
// ---------------------------------------------------------------------------
__global__ __launch_bounds__(256) void phase1_kernel(
    const float* __restrict__ xf, const float* __restrict__ xb,
    const float* __restrict__ Wl, const float* __restrict__ bl,
    const float* __restrict__ Wr, const float* __restrict__ br,
    const int* __restrict__ edst,
    bf16* __restrict__ xl, bf16* __restrict__ xr,
    int* __restrict__ cnt, int* __restrict__ rank)
{
    if (blockIdx.x >= PROJ_BLKS) {
        int e = (blockIdx.x - PROJ_BLKS) * 256 + threadIdx.x;
        if (e < N_EDGES) {
            int x = blockIdx.x & 7;              // XCD-locality heuristic
            int r = atomicAdd(&cnt[x * NPAD + edst[e]], 1);
            rank[e] = (x << 16) | r;
        }
        return;
    }

    int wave = threadIdx.x >> 6;
    int lane = threadIdx.x & 63;
    int n = lane & 15, q = lane >> 4;
    int node0 = blockIdx.x * 64;

    // Build B-frags (hi/lo split of W rows) in registers from f32 W.
    bf16x8 bhi[2][4], blo[2][4];
    float biasv[2], w128[2];
    #pragma unroll
    for (int nt = 0; nt < 2; ++nt) {
        int ch = wave * 32 + nt * 16 + n;
        const float* wrow = (ch < 64) ? (Wl + (size_t)ch * IN_DIM)
                                      : (Wr + (size_t)(ch - 64) * IN_DIM);
        #pragma unroll
        for (int ks = 0; ks < 4; ++ks) {
            bf16x8 hi, lo;
            #pragma unroll
            for (int j = 0; j < 8; ++j) {
                float v = wrow[ks * 32 + q * 8 + j];
                short hs = f2bs(v);
                hi[j] = hs;
                lo[j] = f2bs(v - bs2f(hs));
            }
            bhi[nt][ks] = hi;
            blo[nt][ks] = lo;
        }
        biasv[nt] = (ch < 64) ? bl[ch] : br[ch - 64];
        w128[nt]  = wrow[128];
    }

    #pragma unroll
    for (int mt = 0; mt < 4; ++mt) {
        int nb = node0 + mt * 16;
        if (nb >= N_NODES) break;
        const float* xrow = xf + (size_t)(nb + n) * F_DIM;
        bf16x8 a[4];
        #pragma unroll
        for (int ks = 0; ks < 4; ++ks) {
            float4 u = *(const float4*)(xrow + ks * 32 + q * 8);
            float4 v = *(const float4*)(xrow + ks * 32 + q * 8 + 4);
            bf16x8 t;
            t[0] = f2bs(u.x); t[1] = f2bs(u.y); t[2] = f2bs(u.z); t[3] = f2bs(u.w);
            t[4] = f2bs(v.x); t[5] = f2bs(v.y); t[6] = f2bs(v.z); t[7] = f2bs(v.w);
            a[ks] = t;
        }
        f32x4 acc[2] = {{0.f,0.f,0.f,0.f},{0.f,0.f,0.f,0.f}};
        #pragma unroll
        for (int ks = 0; ks < 4; ++ks) {
            #pragma unroll
            for (int nt = 0; nt < 2; ++nt) {
                acc[nt] = __builtin_amdgcn_mfma_f32_16x16x32_bf16(a[ks], bhi[nt][ks], acc[nt], 0, 0, 0);
                acc[nt] = __builtin_amdgcn_mfma_f32_16x16x32_bf16(a[ks], blo[nt][ks], acc[nt], 0, 0, 0);
            }
        }
        float4 xbv = *(const float4*)(xb + nb + q * 4);
        float xbr[4] = {xbv.x, xbv.y, xbv.z, xbv.w};
        #pragma unroll
        for (int nt = 0; nt < 2; ++nt) {
            int ch = wave * 32 + nt * 16 + n;
            bf16* dstp = (ch < 64) ? xl : xr;
            int cc = ch & 63;
            #pragma unroll
            for (int r = 0; r < 4; ++r) {
                int node = nb + q * 4 + r;   // C/D: row = quad*4 + reg
                float val = acc[nt][r] + xbr[r] * w128[nt] + biasv[nt];
                dstp[(size_t)node * H_DIM + cc] = __float2bfloat16(val);
            }
        }
    }
}

// ---------------------------------------------------------------------------
// CSR scan. Per node: total = sum of 8 per-XCD counts (+1 self-loop slot);
// per-copy exclusive bases stored to base[node*8+x] (one 32 B line/node).
// offs is block-local exclusive; consumers add bsum[node>>8].
// ---------------------------------------------------------------------------
__global__ __launch_bounds__(256) void scan_a_kernel(
    const int* __restrict__ cnt, int* __restrict__ offs,
    int* __restrict__ base, int* __restrict__ bsum)
{
    __shared__ int s[256];
    int tid = threadIdx.x;
    int i = blockIdx.x * 256 + tid;

    int b[8], tot = 0;
    #pragma unroll
    for (int x = 0; x < 8; ++x) {
        int cv = (i < N_NODES) ? cnt[x * NPAD + i] : 0;
        b[x] = tot;                 // exclusive base of copy x within node i
        tot += cv;
    }
    #pragma unroll
    for (int x = 0; x < 8; ++x) base[(size_t)i * 8 + x] = b[x];

    int v = (i < N_NODES) ? tot + 1 : 0;    // +1 = self-loop slot
    s[tid] = v;
    __syncthreads();
    #pragma unroll
    for (int d = 1; d < 256; d <<= 1) {
        int t = (tid >= d) ? s[tid - d] : 0;
        __syncthreads();
        s[tid] += t;
        __syncthreads();
    }
    offs[i] = s[tid] - v;
    if (tid == 255) bsum[blockIdx.x] = s[255];
}

__global__ __launch_bounds__(256) void scan_b_kernel(int* __restrict__ bsum)
{
    __shared__ int s[256];
    int tid = threadIdx.x;
    int v = (tid < 196) ? bsum[tid] : 0;
    s[tid] = v;
    __syncthreads();
    #pragma unroll
    for (int d = 1; d < 256; d <<= 1) {
        int t = (tid >= d) ? s[tid - d] : 0;
        __syncthreads();
        s[tid] += t;
        __syncthreads();
    }
    if (tid < 196) bsum[tid] = s[tid] - v;
}

// ---------------------------------------------------------------------------
// K2a: CSR fill, atomic-free, uint16 entries, 4 edges/thread grid-stride.
// pos = offs[dst] + bsum + 1 + base[dst*8 + copy] + local_rank.
// ---------------------------------------------------------------------------
__global__ __launch_bounds__(256) void fill_kernel(
    const int* __restrict__ esrc, const int* __restrict__ edst,
    const int* __restrict__ offs, const int* __restrict__ bsum,
    const int* __restrict__ base, const int* __restrict__ rank,
    u16* __restrict__ csr_src)
{
    const int t      = blockIdx.x * 256 + threadIdx.x;
    const int stride = FILL_BLKS * 256;
    #pragma unroll
    for (int k = 0; k < 4; ++k) {
        int id = t + k * stride;
        if (id >= ETOT) continue;
        int src, pos;
        if (id < N_EDGES) {
            src = esrc[id];
            int dst = edst[id];
            int r = rank[id];
            int x = r >> 16, rr = r & 0xFFFF;
            pos = offs[dst] + bsum[dst >> 8] + 1 + base[(size_t)dst * 8 + x] + rr;
        } else {
            src = id - N_EDGES;
            pos = offs[src] + bsum[src >> 8];
        }
        csr_src[pos] = (u16)src;
    }
}

// ---------------------------------------------------------------------------
// K2b (fused score + aggregate, wave-per-dst, depth-3 pipeline):
// 2-D lane layout: g = lane>>3 (edge slot, 8/batch), c8 = lane&7 (channel
// octet). Values for batches +1/+2 in flight; indices for +3.
// Dot reduce = 3 shfl_xor per batch; group-combine once per dst.
// ---------------------------------------------------------------------------
__global__ __launch_bounds__(256) void agg_fused(
    const u16* __restrict__ csr_src, const int* __restrict__ offs,
    const int* __restrict__ bsum,
    const bf16* __restrict__ xl, const bf16* __restrict__ xr,
    const float* __restrict__ att, const float* __restrict__ gb,
    bf16* __restrict__ h)
{
    int wid  = (blockIdx.x * 256 + threadIdx.x) >> 6;   // dst node
    int lane = threadIdx.x & 63;
    if (wid >= N_NODES) return;
    int g  = lane >> 3;   // edge slot within batch
    int c8 = lane & 7;    // channel octet

    float attv[8], xrv[8];
    {
        bf16x8 xrow = *(const bf16x8*)(xr + (size_t)wid * H_DIM + c8 * 8);
        float4 a0 = *(const float4*)(att + c8 * 8);
        float4 a1 = *(const float4*)(att + c8 * 8 + 4);
        attv[0] = a0.x; attv[1] = a0.y; attv[2] = a0.z; attv[3] = a0.w;
        attv[4] = a1.x; attv[5] = a1.y; attv[6] = a1.z; attv[7] = a1.w;
        #pragma unroll
        for (int j = 0; j < 8; ++j) xrv[j] = bs2f(xrow[j]);
    }

    int beg = offs[wid] + bsum[wid >> 8];
    int end = offs[wid + 1] + bsum[(wid + 1) >> 8];   // >= beg+1 (self-loop)
    int last = end - 1;
    float den = 0.f;
    float acc[8] = {0.f, 0.f, 0.f, 0.f, 0.f, 0.f, 0.f, 0.f};

    int i0 = beg + g;        i0 = (i0 < end) ? i0 : last;
    int i1 = beg + 8 + g;    i1 = (i1 < end) ? i1 : last;
    int i2 = beg + 16 + g;   i2 = (i2 < end) ? i2 : last;
    int srcC = csr_src[i2];                                    // idx batch+2
    bf16x8 xa = *(const bf16x8*)(xl + (size_t)(int)csr_src[i0] * H_DIM + c8 * 8);
    bf16x8 xb = *(const bf16x8*)(xl + (size_t)(int)csr_src[i1] * H_DIM + c8 * 8);

    for (int base = beg; base < end; base += 8) {
        int i3 = base + 24 + g;  i3 = (i3 < end) ? i3 : last;
        int srcD = csr_src[i3];                                // idx batch+3
        bf16x8 xc = *(const bf16x8*)(xl + (size_t)srcC * H_DIM + c8 * 8);

        bool valid = (base + g) < end;
        float xv[8], p = 0.f;
        #pragma unroll
        for (int j = 0; j < 8; ++j) {
            xv[j] = bs2f(xa[j]);
            float m = xv[j] + xrv[j];
            m = (m > 0.f) ? m : 0.2f * m;
            p += m * attv[j];
        }
        p += __shfl_xor(p, 1);
        p += __shfl_xor(p, 2);
        p += __shfl_xor(p, 4);      // all lanes of group g now hold p_g
        float ex = valid ? __expf(p) : 0.f;
        den += ex;
        #pragma unroll
        for (int j = 0; j < 8; ++j) acc[j] += ex * xv[j];

        xa = xb;
        xb = xc;
        srcC = srcD;
    }

    // combine the 8 edge-groups (once per dst)
    #pragma unroll
    for (int j = 0; j < 8; ++j) {
        acc[j] += __shfl_xor(acc[j], 8);
        acc[j] += __shfl_xor(acc[j], 16);
        acc[j] += __shfl_xor(acc[j], 32);
    }
    den += __shfl_xor(den, 8);
    den += __shfl_xor(den, 16);
    den += __shfl_xor(den, 32);

    if (g == 0) {
        float inv = 1.0f / den;
        float4 g0 = *(const float4*)(gb + c8 * 8);
        float4 g1 = *(const float4*)(gb + c8 * 8 + 4);
        float gbv[8] = {g0.x, g0.y, g0.z, g0.w, g1.x, g1.y, g1.z, g1.w};
        bf16x8 ov;
        #pragma unroll
        for (int j = 0; j < 8; ++j) {
            float v = acc[j] * inv + gbv[j];
            v = (v > 0.f) ? v : expm1f(v);
            ov[j] = f2bs(v);
        }
        *(bf16x8*)(h + (size_t)wid * H_DIM + c8 * 8) = ov;
    }
}

// ---------------------------------------------------------------------------
// K3 (MFMA): logits = h @ Wo^T + bo (+ softplus(dispersion) tail on block 0).
// B-frags (Wo hi/lo) built in registers from f32 Wo, once per block.
// ---------------------------------------------------------------------------
__global__ __launch_bounds__(256) void out_mfma(
    const bf16* __restrict__ h, const float* __restrict__ Wo,
    const float* __restrict__ bo, const float* __restrict__ disp,
    float* __restrict__ out)
{
    if (blockIdx.x == 0 && threadIdx.x < F_DIM) {
        float d = disp[threadIdx.x];
        out[(size_t)N_NODES * F_DIM + threadIdx.x] = (d > 20.f) ? d : log1pf(__expf(d));
    }

    int wave = threadIdx.x >> 6;
    int lane = threadIdx.x & 63;
    int n = lane & 15, q = lane >> 4;
    int node0 = blockIdx.x * 64;

    bf16x8 bhi[2][2], blo[2][2];
    float bov[2];
    #pragma unroll
    for (int nt = 0; nt < 2; ++nt) {
        int ch = wave * 32 + nt * 16 + n;
        const float* wrow = Wo + (size_t)ch * H_DIM;
        #pragma unroll
        for (int ks = 0; ks < 2; ++ks) {
            float4 u = *(const float4*)(wrow + ks * 32 + q * 8);
            float4 v = *(const float4*)(wrow + ks * 32 + q * 8 + 4);
            float w[8] = {u.x, u.y, u.z, u.w, v.x, v.y, v.z, v.w};
            bf16x8 hi, lo;
            #pragma unroll
            for (int j = 0; j < 8; ++j) {
                short hs = f2bs(w[j]);
                hi[j] = hs;
                lo[j] = f2bs(w[j] - bs2f(hs));
            }
            bhi[nt][ks] = hi;
            blo[nt][ks] = lo;
        }
        bov[nt] = bo[ch];
    }

    #pragma unroll
    for (int mt = 0; mt < 4; ++mt) {
        int nb = node0 + mt * 16;
        if (nb >= N_NODES) break;
        const bf16* hrow = h + (size_t)(nb + n) * H_DIM;
        bf16x8 a[2];
        #pragma unroll
        for (int ks = 0; ks < 2; ++ks)
            a[ks] = *(const bf16x8*)(hrow + ks * 32 + q * 8);
        f32x4 acc[2] = {{0.f,0.f,0.f,0.f},{0.f,0.f,0.f,0.f}};
        #pragma unroll
        for (int ks = 0; ks < 2; ++ks) {
            #pragma unroll
            for (int nt = 0; nt < 2; ++nt) {
                acc[nt] = __builtin_amdgcn_mfma_f32_16x16x32_bf16(a[ks], bhi[nt][ks], acc[nt], 0, 0, 0);
                acc[nt] = __builtin_amdgcn_mfma_f32_16x16x32_bf16(a[ks], blo[nt][ks], acc[nt], 0, 0, 0);
            }
        }
        #pragma unroll
        for (int nt = 0; nt < 2; ++nt) {
            int ch = wave * 32 + nt * 16 + n;
            #pragma unroll
            for (int r = 0; r < 4; ++r) {
                int node = nb + q * 4 + r;
                out[(size_t)node * F_DIM + ch] = acc[nt][r] + bov[nt];
            }
        }
    }
}

// ---------------------------------------------------------------------------
extern "C" void kernel_launch(void* const* d_in, const int* in_sizes, int n_in,
                              void* d_out, int out_size, void* d_ws, size_t ws_size,
                              hipStream_t stream)
{
    const float* xf  = (const float*)d_in[0];
    const float* xb  = (const float*)d_in[1];
    const int*   ei  = (const int*)d_in[2];    // [2, E] int32, row-major
    const float* Wl  = (const float*)d_in[3];
    const float* bl  = (const float*)d_in[4];
    const float* Wr  = (const float*)d_in[5];
    const float* br  = (const float*)d_in[6];
    const float* att = (const float*)d_in[7];
    const float* gb  = (const float*)d_in[8];
    const float* Wo  = (const float*)d_in[9];
    const float* bo  = (const float*)d_in[10];
    const float* dp  = (const float*)d_in[11];
    float* out = (float*)d_out;
    const int* esrc = ei;
    const int* edst = ei + N_EDGES;

    // ws layout (16B-aligned segments):
    //  xl bf16[N*64] | xr bf16[N*64] | h bf16[N*64] | csr_src u16[ETOT] |
    //  rank int[E] | cnt int[8*NPAD] | offs int[NPAD] | base int[8*NPAD] |
    //  bsum int[256]
    char* ws = (char*)d_ws;
    const size_t SZB = (size_t)N_NODES * H_DIM * sizeof(bf16);   // 6.4 MB
    bf16*  xl      = (bf16*)(ws);
    bf16*  xr      = (bf16*)(ws + SZB);
    bf16*  h       = (bf16*)(ws + 2 * SZB);
    u16*   csr_src = (u16*)(ws + 3 * SZB);
    int*   rank    = (int*)(ws + 3 * SZB + (size_t)((ETOT + 1) & ~1) * 2);
    int*   cnt     = rank + N_EDGES;
    int*   offs    = cnt + 8 * NPAD;
    int*   base    = offs + NPAD;
    int*   bsum    = base + 8 * NPAD;

    hipMemsetAsync(cnt, 0, 8 * NPAD * sizeof(int), stream);

    phase1_kernel<<<PROJ_BLKS + CNT_BLKS, 256, 0, stream>>>(
        xf, xb, Wl, bl, Wr, br, edst, xl, xr, cnt, rank);

    scan_a_kernel<<<NPAD / 256, 256, 0, stream>>>(cnt, offs, base, bsum);
    scan_b_kernel<<<1, 256, 0, stream>>>(bsum);

    fill_kernel<<<FILL_BLKS, 256, 0, stream>>>(esrc, edst, offs, bsum, base,
                                               rank, csr_src);

    agg_fused<<<(N_NODES * 64) / 256, 256, 0, stream>>>(csr_src, offs, bsum,
                                                        xl, xr, att, gb, h);

    out_mfma<<<(N_NODES + 63) / 64, 256, 0, stream>>>(h, Wo, bo, dp, out);
}